// Round 11
// baseline (3840.635 us; speedup 1.0000x reference)
//
#include <hip/hip_runtime.h>
#include <hip/hip_bf16.h>

typedef __attribute__((ext_vector_type(8))) short bf16x8;
typedef __attribute__((ext_vector_type(4))) float f32x4;
typedef __attribute__((ext_vector_type(4))) unsigned int u32x4;

#define BB 32
#define SS 512
#define DD 512
#define HH 1024
#define KTOT (DD + HH)      // 1536
#define NCH 8               // h-columns per block
#define NCOL 32             // 4 gates x 8 cols
#define NBLK 256
#define GBLK 128            // blocks per group
#define NB2 16              // batches per group
#define HW2 (HH / 2)        // h row in u64 units (tag + 2 bf16)

// Per-step tagged mailbox: u64 = {hi: tag = step+1, lo: 2 packed bf16}.
// One address per (step, batch, col-pair): written once per replay with
// deterministic values -> consumers may use NORMAL CACHED loads (stale
// lines are value-identical; cold lines fetch through IF; memory-side L3
// is never stale). Tags verified after load; rare mismatch -> sc0sc1 retry.
__device__ unsigned long long g_mail[(size_t)SS * BB * HW2];   // 64 MB
__device__ unsigned int g_flag[NBLK * 16];   // per-block step flag, 64B-padded
__device__ unsigned int g_done;              // end-of-run reset rendezvous

struct Params {
    const float* x;        // [B][S][D] fp32
    const float* Wi[4];    // [D][H]
    const float* Wh[4];    // [H][H]
    const float* bias[4];  // [H]
    float* out_h;          // [B][S][H] fp32
    float* out_c;          // [B][S][H] fp32
};

static __device__ __forceinline__ short f2bf(float f) {
    __hip_bfloat16 h = __float2bfloat16(f);
    return *reinterpret_cast<short*>(&h);
}

static __device__ __forceinline__ unsigned ldflag(int slot) {
    return __hip_atomic_load(&g_flag[slot << 4], __ATOMIC_RELAXED,
                             __HIP_MEMORY_SCOPE_AGENT);
}

__launch_bounds__(256, 1)
__global__ void lstm_mfma(Params p) {
    // Fragment-major B: Wb[k8][col][8] -> 16 consecutive cols read 16
    // consecutive 16B fragments (conflict-free ds_read_b128).
    __shared__ short Wb[(KTOT / 8) * NCOL * 8];   // 96 KB
    __shared__ float accl[2][NB2][NCOL];          // [k-half][batch][gate-col]
    __shared__ float c_st[NB2][NCH];              // fp32 cell state
    __shared__ float bias_l[NCOL];
    __shared__ unsigned rel;              // LDS relay: last step whose h is ready

    const int tid = threadIdx.x;
    const int blk = blockIdx.x;
    const int gid = blk & 1;              // batch group
    const int lid = blk >> 1;             // 0..127 within group
    const int bb0 = gid * NB2;            // first batch row
    const int hc0 = lid * NCH;            // first h column

    if (tid == 0)
        __hip_atomic_store(&rel, 0u, __ATOMIC_RELAXED, __HIP_MEMORY_SCOPE_WORKGROUP);

    // ---- stage weights to LDS once (coalesced f32x4 rows) ----
    for (int idx = tid; idx < KTOT * 8; idx += 256) {
        const int r = idx >> 3, q = idx & 7;
        const int g = q >> 1, half = (q & 1) * 4;
        f32x4 w = (r < DD)
            ? *(const f32x4*)&p.Wi[g][(size_t)r * HH + hc0 + half]
            : *(const f32x4*)&p.Wh[g][(size_t)(r - DD) * HH + hc0 + half];
        #pragma unroll
        for (int jj = 0; jj < 4; ++jj)
            Wb[(((r >> 3) * NCOL + g * 8 + half + jj) << 3) + (r & 7)] = f2bf(w[jj]);
    }
    if (tid < NCOL) bias_l[tid] = p.bias[tid >> 3][hc0 + (tid & 7)];
    __syncthreads();

    const int wave = tid >> 6;
    const int lane = tid & 63;
    const int ct  = wave & 1;               // col-tile (16 gate-cols each)
    const int kh  = wave >> 1;              // K half
    const int arow = bb0 + (lane & 15);     // global batch row for A
    const int gc  = ct * 16 + (lane & 15);  // gate-col for B
    const int kg  = lane >> 4;              // k-subgroup 0..3
    const int kgb = kg * 8;

    // LDS fragment bases (bf16x8-aligned, conflict-free)
    const short* xB = &Wb[(((kh * 32 + kg) * NCOL + gc) << 3)];
    const short* hB = &Wb[(((64 + kh * 64 + kg) * NCOL + gc) << 3)];

    // x-part for one step (8 chunks/wave: k = kh*256 + cx*32 + kg*8)
    auto xpart = [&](int t, f32x4 a_cc) -> f32x4 {
        const float* xrow = p.x + ((size_t)arow * SS + t) * DD;
        #pragma unroll 4
        for (int cx = 0; cx < 8; ++cx) {
            const int k0 = kh * 256 + cx * 32 + kgb;
            f32x4 a0 = *(const f32x4*)(xrow + k0);
            f32x4 a1 = *(const f32x4*)(xrow + k0 + 4);
            bf16x8 a;
            a[0] = f2bf(a0[0]); a[1] = f2bf(a0[1]);
            a[2] = f2bf(a0[2]); a[3] = f2bf(a0[3]);
            a[4] = f2bf(a1[0]); a[5] = f2bf(a1[1]);
            a[6] = f2bf(a1[2]); a[7] = f2bf(a1[3]);
            a_cc = __builtin_amdgcn_mfma_f32_16x16x32_bf16(
                a, *(const bf16x8*)(xB + (size_t)cx * 1024), a_cc, 0, 0, 0);
        }
        return a_cc;
    };

    f32x4 acc = {0.f, 0.f, 0.f, 0.f};
    acc = xpart(0, acc);                   // prologue: x-part of t=0

    for (int t = 0; t < SS; ++t) {
        if (t > 0) {
            // ---- gate: all group blocks published step t-1 (flags >= t) ----
            if (wave == 0) {
                const int s0 = gid * GBLK + lane * 2;
                unsigned it = 0;
                for (;;) {
                    unsigned v0 = ldflag(s0), v1 = ldflag(s0 + 1);
                    if (__all(min(v0, v1) >= (unsigned)t)) break;
                    __builtin_amdgcn_s_sleep(2);
                    if (++it > (1u << 20)) break;   // fail loud, not hang
                }
                if (lane == 0)
                    __hip_atomic_store(&rel, (unsigned)t, __ATOMIC_RELAXED,
                                       __HIP_MEMORY_SCOPE_WORKGROUP);
            } else {
                unsigned it = 0;
                while (__hip_atomic_load(&rel, __ATOMIC_RELAXED,
                                         __HIP_MEMORY_SCOPE_WORKGROUP) < (unsigned)t) {
                    __builtin_amdgcn_s_sleep(1);
                    if (++it > (1u << 22)) break;
                }
            }
            asm volatile("" ::: "memory");

            // ---- bulk h read: NORMAL cached loads (L2-served), tag-verified ----
            const unsigned long long* hb = g_mail
                + (size_t)(t - 1) * (BB * HW2)
                + (size_t)arow * HW2 + kh * 256 + kg * 4;
            const unsigned tg = (unsigned)t;   // producer stored step+1 = t
            u32x4 r00,r01,r02,r03,r04,r05,r06,r07,r08,r09,r10,r11,r12,r13,r14,r15,
                  r16,r17,r18,r19,r20,r21,r22,r23,r24,r25,r26,r27,r28,r29,r30,r31;
#define LDALL(SFX)                                                                  \
            do {                                                                    \
                LDH(r00,"0");    LDH(r01,"16");   LDH(r02,"128");  LDH(r03,"144");  \
                LDH(r04,"256");  LDH(r05,"272");  LDH(r06,"384");  LDH(r07,"400");  \
                LDH(r08,"512");  LDH(r09,"528");  LDH(r10,"640");  LDH(r11,"656");  \
                LDH(r12,"768");  LDH(r13,"784");  LDH(r14,"896");  LDH(r15,"912");  \
                LDH(r16,"1024"); LDH(r17,"1040"); LDH(r18,"1152"); LDH(r19,"1168"); \
                LDH(r20,"1280"); LDH(r21,"1296"); LDH(r22,"1408"); LDH(r23,"1424"); \
                LDH(r24,"1536"); LDH(r25,"1552"); LDH(r26,"1664"); LDH(r27,"1680"); \
                LDH(r28,"1792"); LDH(r29,"1808"); LDH(r30,"1920"); LDH(r31,"1936"); \
            } while (0)
#define TAGOK(r) ((r[1] == tg) & (r[3] == tg))
#define TAGCHK (TAGOK(r00) & TAGOK(r01) & TAGOK(r02) & TAGOK(r03)               \
              & TAGOK(r04) & TAGOK(r05) & TAGOK(r06) & TAGOK(r07)               \
              & TAGOK(r08) & TAGOK(r09) & TAGOK(r10) & TAGOK(r11)               \
              & TAGOK(r12) & TAGOK(r13) & TAGOK(r14) & TAGOK(r15)               \
              & TAGOK(r16) & TAGOK(r17) & TAGOK(r18) & TAGOK(r19)               \
              & TAGOK(r20) & TAGOK(r21) & TAGOK(r22) & TAGOK(r23)               \
              & TAGOK(r24) & TAGOK(r25) & TAGOK(r26) & TAGOK(r27)               \
              & TAGOK(r28) & TAGOK(r29) & TAGOK(r30) & TAGOK(r31))
            bool ok;
            {
#define LDH(dst, OFF) asm volatile("global_load_dwordx4 %0, %1, off offset:" OFF \
                                   : "=v"(dst) : "v"(hb))
                LDALL(n);
#undef LDH
                asm volatile("s_waitcnt vmcnt(0)" ::: "memory");
                __builtin_amdgcn_sched_barrier(0);
                ok = TAGCHK;
            }
            if (!__all(ok)) {              // rare: fresh coherent retry
                unsigned it = 0;
                do {
                    __builtin_amdgcn_s_sleep(1);
#define LDH(dst, OFF) asm volatile("global_load_dwordx4 %0, %1, off offset:" OFF \
                                   " sc0 sc1" : "=v"(dst) : "v"(hb))
                    LDALL(c);
#undef LDH
                    asm volatile("s_waitcnt vmcnt(0)" ::: "memory");
                    __builtin_amdgcn_sched_barrier(0);
                    ok = TAGCHK;
                } while (!__all(ok) && ++it < (1u << 18));
            }
#undef TAGCHK
#undef TAGOK
#undef LDALL
            __builtin_amdgcn_sched_barrier(0);
#define FMH(CH, RA, RB) { bf16x8 a_; unsigned* au = (unsigned*)&a_;            \
                au[0] = RA[0]; au[1] = RA[2]; au[2] = RB[0]; au[3] = RB[2];     \
                acc = __builtin_amdgcn_mfma_f32_16x16x32_bf16(                 \
                    a_, *(const bf16x8*)(hB + (CH) * 1024), acc, 0, 0, 0); }
            FMH(0,  r00, r01); FMH(1,  r02, r03); FMH(2,  r04, r05); FMH(3,  r06, r07);
            FMH(4,  r08, r09); FMH(5,  r10, r11); FMH(6,  r12, r13); FMH(7,  r14, r15);
            FMH(8,  r16, r17); FMH(9,  r18, r19); FMH(10, r20, r21); FMH(11, r22, r23);
            FMH(12, r24, r25); FMH(13, r26, r27); FMH(14, r28, r29); FMH(15, r30, r31);
#undef FMH
        }
        #pragma unroll
        for (int i = 0; i < 4; ++i)
            accl[kh][(lane >> 4) * 4 + i][gc] = acc[i];
        __syncthreads();

        if (tid < 64) {                    // gating: lane -> (batch, col-pair)
            const int b = lane >> 2, jp = (lane & 3) * 2;
            float hn2[2], cn2[2];
            #pragma unroll
            for (int u = 0; u < 2; ++u) {
                const int j = jp + u;
                float pre[4];
                #pragma unroll
                for (int g = 0; g < 4; ++g) {
                    const int c = g * 8 + j;
                    pre[g] = accl[0][b][c] + accl[1][b][c] + bias_l[c];
                }
                const float ig = 1.f / (1.f + __expf(-pre[0]));
                const float fg = 1.f / (1.f + __expf(-pre[1]));
                const float gg = tanhf(pre[2]);
                const float og = 1.f / (1.f + __expf(-pre[3]));
                const float cp = (t == 0) ? 0.f : c_st[b][j];
                const float cn = fg * cp + ig * gg;
                const float hn = og * tanhf(cn);
                c_st[b][j] = cn;
                hn2[u] = hn; cn2[u] = cn;
            }
            const unsigned pack = (unsigned)(unsigned short)f2bf(hn2[0])
                                | ((unsigned)(unsigned short)f2bf(hn2[1]) << 16);
            const unsigned long long v =
                ((unsigned long long)(unsigned)(t + 1) << 32) | pack;
            __hip_atomic_store(
                &g_mail[(size_t)t * (BB * HW2) + (bb0 + b) * HW2 + ((hc0 + jp) >> 1)],
                v, __ATOMIC_RELAXED, __HIP_MEMORY_SCOPE_AGENT);
            // wave-level ack: all lanes' mailbox stores at the coherence point
            asm volatile("s_waitcnt vmcnt(0)" ::: "memory");
            if (lane == 0 && t < SS - 1)
                __hip_atomic_store(&g_flag[(gid * GBLK + lid) << 4], (unsigned)(t + 1),
                                   __ATOMIC_RELAXED, __HIP_MEMORY_SCOPE_AGENT);
            // fp32 outputs off the critical path, after the publish
            const size_t o = ((size_t)(bb0 + b) * SS + t) * HH + hc0 + jp;
            *(float2*)&p.out_h[o] = make_float2(hn2[0], hn2[1]);
            *(float2*)&p.out_c[o] = make_float2(cn2[0], cn2[1]);
        }
        if (t == SS - 1) break;
        // ---- overlap publish latency: x-part of t+1 (h-independent) ----
        acc = (f32x4){0.f, 0.f, 0.f, 0.f};
        acc = xpart(t + 1, acc);
        // close the accl t/t+1 race (gating reads vs next h-part writes)
        __syncthreads();
    }

    // ---- end-of-run: last block resets flags for the next graph replay ----
    __syncthreads();
    if (tid == 0) {
        unsigned v = __hip_atomic_fetch_add(&g_done, 1u, __ATOMIC_RELAXED,
                                            __HIP_MEMORY_SCOPE_AGENT) + 1;
        if (v == NBLK) {
            for (int i = 0; i < NBLK; ++i)
                __hip_atomic_store(&g_flag[i << 4], 0u, __ATOMIC_RELAXED,
                                   __HIP_MEMORY_SCOPE_AGENT);
            __hip_atomic_store(&g_done, 0u, __ATOMIC_RELAXED,
                               __HIP_MEMORY_SCOPE_AGENT);
        }
    }
}

extern "C" void kernel_launch(void* const* d_in, const int* in_sizes, int n_in,
                              void* d_out, int out_size, void* d_ws, size_t ws_size,
                              hipStream_t stream) {
    (void)in_sizes; (void)n_in; (void)d_ws; (void)ws_size; (void)out_size;
    Params p;
    p.x = (const float*)d_in[0];
    for (int g = 0; g < 4; ++g) {
        p.Wi[g]   = (const float*)d_in[1 + g];
        p.Wh[g]   = (const float*)d_in[5 + g];
        p.bias[g] = (const float*)d_in[9 + g];
    }
    p.out_h = (float*)d_out;
    p.out_c = p.out_h + (size_t)BB * SS * HH;
    lstm_mfma<<<dim3(NBLK), dim3(256), 0, stream>>>(p);
}

// Round 13
// 2591.316 us; speedup vs baseline: 1.4821x; 1.4821x over previous
//
#include <hip/hip_runtime.h>
#include <hip/hip_bf16.h>

typedef __attribute__((ext_vector_type(8))) short bf16x8;
typedef __attribute__((ext_vector_type(4))) float f32x4;

#define BB 32
#define SS 512
#define DD 512
#define HH 1024
#define KTOT (DD + HH)      // 1536
#define NCH 8               // h-columns per block
#define NCOL 32             // 4 gates x 8 cols
#define NBLK 256
#define GBLK 128            // blocks per group
#define NB2 16              // batches per group
#define HW2 (HH / 2)        // h row in packed u32 (2 bf16 each)

// Cross-block state: zero-initialized device globals, self-reset each run.
__device__ unsigned int g_flag[NBLK * 16];        // per-block step flag, 64B-padded
__device__ unsigned int g_done;                   // end-of-run reset rendezvous
__device__ unsigned int g_hws[2 * BB * HW2];      // bf16-pair h ping-pong

struct Params {
    const float* x;        // [B][S][D] fp32
    const float* Wi[4];    // [D][H]
    const float* Wh[4];    // [H][H]
    const float* bias[4];  // [H]
    float* out_h;          // [B][S][H] fp32
    float* out_c;          // [B][S][H] fp32
};

static __device__ __forceinline__ short f2bf(float f) {
    __hip_bfloat16 h = __float2bfloat16(f);
    return *reinterpret_cast<short*>(&h);
}

static __device__ __forceinline__ unsigned ldflag(int slot) {
    return __hip_atomic_load(&g_flag[slot << 4], __ATOMIC_RELAXED,
                             __HIP_MEMORY_SCOPE_AGENT);
}

__launch_bounds__(256, 1)
__global__ void lstm_mfma(Params p) {
    // Fragment-major B: Wb[k8][col][8] -> 16 consecutive cols read 16
    // consecutive 16B fragments (conflict-free ds_read_b128). Proven r9-r11.
    __shared__ short Wb[(KTOT / 8) * NCOL * 8];   // 96 KB
    __shared__ float accl[2][NB2][NCOL];          // [k-half][batch][gate-col]
    __shared__ float c_st[NB2][NCH];              // fp32 cell state
    __shared__ float bias_l[NCOL];
    __shared__ unsigned rel;              // LDS relay: last step whose h is ready

    const int tid = threadIdx.x;
    const int blk = blockIdx.x;
    const int gid = blk & 1;              // batch group
    const int lid = blk >> 1;             // 0..127 within group
    const int bb0 = gid * NB2;            // first batch row
    const int hc0 = lid * NCH;            // first h column

    if (tid == 0)
        __hip_atomic_store(&rel, 0u, __ATOMIC_RELAXED, __HIP_MEMORY_SCOPE_WORKGROUP);

    // ---- stage weights to LDS once (coalesced f32x4 rows) ----
    for (int idx = tid; idx < KTOT * 8; idx += 256) {
        const int r = idx >> 3, q = idx & 7;
        const int g = q >> 1, half = (q & 1) * 4;
        f32x4 w = (r < DD)
            ? *(const f32x4*)&p.Wi[g][(size_t)r * HH + hc0 + half]
            : *(const f32x4*)&p.Wh[g][(size_t)(r - DD) * HH + hc0 + half];
        #pragma unroll
        for (int jj = 0; jj < 4; ++jj)
            Wb[(((r >> 3) * NCOL + g * 8 + half + jj) << 3) + (r & 7)] = f2bf(w[jj]);
    }
    if (tid < NCOL) bias_l[tid] = p.bias[tid >> 3][hc0 + (tid & 7)];
    __syncthreads();

    const int wave = tid >> 6;
    const int lane = tid & 63;
    const int ct  = wave & 1;               // col-tile (16 gate-cols each)
    const int kh  = wave >> 1;              // K half
    const int arow = bb0 + (lane & 15);     // global batch row for A
    const int gc  = ct * 16 + (lane & 15);  // gate-col for B
    const int kg  = lane >> 4;              // k-subgroup 0..3
    const int kgb = kg * 8;

    // LDS fragment bases (bf16x8-aligned, conflict-free)
    const short* xB = &Wb[(((kh * 32 + kg) * NCOL + gc) << 3)];
    const short* hB = &Wb[(((64 + kh * 64 + kg) * NCOL + gc) << 3)];

    // x-part for one step (8 chunks/wave: k = kh*256 + cx*32 + kg*8)
    auto xpart = [&](int t, f32x4 a_cc) -> f32x4 {
        const float* xrow = p.x + ((size_t)arow * SS + t) * DD;
        #pragma unroll 4
        for (int cx = 0; cx < 8; ++cx) {
            const int k0 = kh * 256 + cx * 32 + kgb;
            f32x4 a0 = *(const f32x4*)(xrow + k0);
            f32x4 a1 = *(const f32x4*)(xrow + k0 + 4);
            bf16x8 a;
            a[0] = f2bf(a0[0]); a[1] = f2bf(a0[1]);
            a[2] = f2bf(a0[2]); a[3] = f2bf(a0[3]);
            a[4] = f2bf(a1[0]); a[5] = f2bf(a1[1]);
            a[6] = f2bf(a1[2]); a[7] = f2bf(a1[3]);
            a_cc = __builtin_amdgcn_mfma_f32_16x16x32_bf16(
                a, *(const bf16x8*)(xB + (size_t)cx * 1024), a_cc, 0, 0, 0);
        }
        return a_cc;
    };

    f32x4 acc = {0.f, 0.f, 0.f, 0.f};
    acc = xpart(0, acc);                   // prologue: x-part of t=0

    for (int t = 0; t < SS; ++t) {
        if (t > 0) {
            // ---- wait: all 128 group blocks finished step t-1 ----
            if (wave == 0) {
                const int s0 = gid * GBLK + lane * 2;
                unsigned it = 0;
                for (;;) {
                    unsigned v0 = ldflag(s0), v1 = ldflag(s0 + 1);
                    if (__all(min(v0, v1) >= (unsigned)t)) break;
                    __builtin_amdgcn_s_sleep(2);
                    if (++it > (1u << 20)) break;   // fail loud, not hang
                }
                if (lane == 0)
                    __hip_atomic_store(&rel, (unsigned)t, __ATOMIC_RELAXED,
                                       __HIP_MEMORY_SCOPE_WORKGROUP);
            } else {
                unsigned it = 0;
                while (__hip_atomic_load(&rel, __ATOMIC_RELAXED,
                                         __HIP_MEMORY_SCOPE_WORKGROUP) < (unsigned)t) {
                    __builtin_amdgcn_s_sleep(1);
                    if (++it > (1u << 22)) break;
                }
            }
            asm volatile("" ::: "memory");

            // ---- h-part: 16 batched coherent 16B loads, split-wait MFMAs ----
            {
                const unsigned* hb = g_hws + ((t - 1) & 1) * (BB * HW2)
                                   + (size_t)arow * HW2 + kh * 256 + kg * 4;
                bf16x8 h00,h01,h02,h03,h04,h05,h06,h07,
                       h08,h09,h10,h11,h12,h13,h14,h15;
#define LDH(dst, OFF) asm volatile("global_load_dwordx4 %0, %1, off offset:" OFF " sc0 sc1" \
                                   : "=v"(dst) : "v"(hb))
                LDH(h00, "0");   LDH(h01, "64");  LDH(h02, "128"); LDH(h03, "192");
                LDH(h04, "256"); LDH(h05, "320"); LDH(h06, "384"); LDH(h07, "448");
                LDH(h08, "512"); LDH(h09, "576"); LDH(h10, "640"); LDH(h11, "704");
                LDH(h12, "768"); LDH(h13, "832"); LDH(h14, "896"); LDH(h15, "960");
#undef LDH
#define FMH(v, CH) acc = __builtin_amdgcn_mfma_f32_16x16x32_bf16( \
                        (v), *(const bf16x8*)(hB + (CH) * 1024), acc, 0, 0, 0)
                asm volatile("s_waitcnt vmcnt(8)" ::: "memory");
                __builtin_amdgcn_sched_barrier(0);
                FMH(h00, 0);  FMH(h01, 1);  FMH(h02, 2);  FMH(h03, 3);
                FMH(h04, 4);  FMH(h05, 5);  FMH(h06, 6);  FMH(h07, 7);
                asm volatile("s_waitcnt vmcnt(0)" ::: "memory");
                __builtin_amdgcn_sched_barrier(0);
                FMH(h08, 8);  FMH(h09, 9);  FMH(h10, 10); FMH(h11, 11);
                FMH(h12, 12); FMH(h13, 13); FMH(h14, 14); FMH(h15, 15);
#undef FMH
            }
        }
        #pragma unroll
        for (int i = 0; i < 4; ++i)
            accl[kh][(lane >> 4) * 4 + i][gc] = acc[i];
        __syncthreads();

        if (tid < 64) {                    // gating: lane -> (batch, col-pair)
            const int b = lane >> 2, jp = (lane & 3) * 2;
            float hn2[2], cn2[2];
            #pragma unroll
            for (int u = 0; u < 2; ++u) {
                const int j = jp + u;
                float pre[4];
                #pragma unroll
                for (int g = 0; g < 4; ++g) {
                    const int c = g * 8 + j;
                    pre[g] = accl[0][b][c] + accl[1][b][c] + bias_l[c];
                }
                const float ig = 1.f / (1.f + __expf(-pre[0]));
                const float fg = 1.f / (1.f + __expf(-pre[1]));
                const float gg = tanhf(pre[2]);
                const float og = 1.f / (1.f + __expf(-pre[3]));
                const float cp = (t == 0) ? 0.f : c_st[b][j];
                const float cn = fg * cp + ig * gg;
                const float hn = og * tanhf(cn);
                c_st[b][j] = cn;
                hn2[u] = hn; cn2[u] = cn;
            }
            const unsigned pack = (unsigned)(unsigned short)f2bf(hn2[0])
                                | ((unsigned)(unsigned short)f2bf(hn2[1]) << 16);
            __hip_atomic_store(
                &g_hws[(t & 1) * (BB * HW2) + (bb0 + b) * HW2 + ((hc0 + jp) >> 1)],
                pack, __ATOMIC_RELAXED, __HIP_MEMORY_SCOPE_AGENT);
            // wave-level ack: all lanes' h-stores reached the coherence point
            asm volatile("s_waitcnt vmcnt(0)" ::: "memory");
            if (lane == 0 && t < SS - 1)
                __hip_atomic_store(&g_flag[(gid * GBLK + lid) << 4], (unsigned)(t + 1),
                                   __ATOMIC_RELAXED, __HIP_MEMORY_SCOPE_AGENT);
            // fp32 outputs off the critical path, after the flag
            const size_t o = ((size_t)(bb0 + b) * SS + t) * HH + hc0 + jp;
            *(float2*)&p.out_h[o] = make_float2(hn2[0], hn2[1]);
            *(float2*)&p.out_c[o] = make_float2(cn2[0], cn2[1]);
        }
        if (t == SS - 1) break;
        // ---- hide barrier propagation: x-part of t+1 (h-independent) ----
        acc = (f32x4){0.f, 0.f, 0.f, 0.f};
        acc = xpart(t + 1, acc);
    }

    // ---- end-of-run: last block resets flags for the next graph replay ----
    __syncthreads();
    if (tid == 0) {
        unsigned v = __hip_atomic_fetch_add(&g_done, 1u, __ATOMIC_RELAXED,
                                            __HIP_MEMORY_SCOPE_AGENT) + 1;
        if (v == NBLK) {
            for (int i = 0; i < NBLK; ++i)
                __hip_atomic_store(&g_flag[i << 4], 0u, __ATOMIC_RELAXED,
                                   __HIP_MEMORY_SCOPE_AGENT);
            __hip_atomic_store(&g_done, 0u, __ATOMIC_RELAXED,
                               __HIP_MEMORY_SCOPE_AGENT);
        }
    }
}

extern "C" void kernel_launch(void* const* d_in, const int* in_sizes, int n_in,
                              void* d_out, int out_size, void* d_ws, size_t ws_size,
                              hipStream_t stream) {
    (void)in_sizes; (void)n_in; (void)d_ws; (void)ws_size; (void)out_size;
    Params p;
    p.x = (const float*)d_in[0];
    for (int g = 0; g < 4; ++g) {
        p.Wi[g]   = (const float*)d_in[1 + g];
        p.Wh[g]   = (const float*)d_in[5 + g];
        p.bias[g] = (const float*)d_in[9 + g];
    }
    p.out_h = (float*)d_out;
    p.out_c = p.out_h + (size_t)BB * SS * HH;
    lstm_mfma<<<dim3(NBLK), dim3(256), 0, stream>>>(p);
}

// Round 14
// 2132.341 us; speedup vs baseline: 1.8011x; 1.2152x over previous
//
#include <hip/hip_runtime.h>
#include <hip/hip_bf16.h>

typedef __attribute__((ext_vector_type(8))) short bf16x8;
typedef __attribute__((ext_vector_type(4))) float f32x4;
typedef __attribute__((ext_vector_type(4))) unsigned int u32x4;

#define BB 32
#define SS 512
#define DD 512
#define HH 1024
#define KTOT (DD + HH)      // 1536
#define NCH 8               // h-columns per block
#define NCOL 32             // 4 gates x 8 cols
#define NBLK 256
#define GBLK 128            // blocks per group
#define NB2 16              // batches per group
#define HW2 (HH / 2)        // h row in packed u32 (2 bf16 each)
#define LROW 516            // htile row stride in u32 (2064 B: 4-bank rotate/row)

// Cross-block state: zero-initialized device globals, self-reset each run.
__device__ unsigned int g_flag[NBLK * 16];        // per-block step flag, 64B-padded
__device__ unsigned int g_done;                   // end-of-run reset rendezvous
__device__ unsigned int g_hws[2 * BB * HW2];      // bf16-pair h ping-pong

struct Params {
    const float* x;        // [B][S][D] fp32
    const float* Wi[4];    // [D][H]
    const float* Wh[4];    // [H][H]
    const float* bias[4];  // [H]
    float* out_h;          // [B][S][H] fp32
    float* out_c;          // [B][S][H] fp32
};

static __device__ __forceinline__ short f2bf(float f) {
    __hip_bfloat16 h = __float2bfloat16(f);
    return *reinterpret_cast<short*>(&h);
}

static __device__ __forceinline__ unsigned ldflag(int slot) {
    return __hip_atomic_load(&g_flag[slot << 4], __ATOMIC_RELAXED,
                             __HIP_MEMORY_SCOPE_AGENT);
}

__launch_bounds__(256, 1)
__global__ void lstm_mfma(Params p) {
    // Fragment-major B: Wb[k8][col][8] -> 16 consecutive cols read 16
    // consecutive 16B fragments (conflict-free ds_read_b128). Proven r9-r13.
    __shared__ short Wb[(KTOT / 8) * NCOL * 8];   // 96 KB
    __shared__ __align__(16) unsigned htile[NB2 * LROW];  // 33 KB h tile (dedup)
    __shared__ float accl[2][NB2][NCOL];          // [k-half][batch][gate-col]
    __shared__ float c_st[NB2][NCH];              // fp32 cell state
    __shared__ float bias_l[NCOL];
    __shared__ unsigned rel;              // LDS relay: last step whose h is ready

    const int tid = threadIdx.x;
    const int blk = blockIdx.x;
    const int gid = blk & 1;              // batch group
    const int lid = blk >> 1;             // 0..127 within group
    const int bb0 = gid * NB2;            // first batch row
    const int hc0 = lid * NCH;            // first h column

    if (tid == 0)
        __hip_atomic_store(&rel, 0u, __ATOMIC_RELAXED, __HIP_MEMORY_SCOPE_WORKGROUP);

    // ---- stage weights to LDS once (coalesced f32x4 rows) ----
    for (int idx = tid; idx < KTOT * 8; idx += 256) {
        const int r = idx >> 3, q = idx & 7;
        const int g = q >> 1, half = (q & 1) * 4;
        f32x4 w = (r < DD)
            ? *(const f32x4*)&p.Wi[g][(size_t)r * HH + hc0 + half]
            : *(const f32x4*)&p.Wh[g][(size_t)(r - DD) * HH + hc0 + half];
        #pragma unroll
        for (int jj = 0; jj < 4; ++jj)
            Wb[(((r >> 3) * NCOL + g * 8 + half + jj) << 3) + (r & 7)] = f2bf(w[jj]);
    }
    if (tid < NCOL) bias_l[tid] = p.bias[tid >> 3][hc0 + (tid & 7)];
    __syncthreads();

    const int wave = tid >> 6;
    const int lane = tid & 63;
    const int ct  = wave & 1;               // col-tile (16 gate-cols each)
    const int kh  = wave >> 1;              // K half
    const int arow = bb0 + (lane & 15);     // global batch row for A (x-part)
    const int gc  = ct * 16 + (lane & 15);  // gate-col for B
    const int kg  = lane >> 4;              // k-subgroup 0..3
    const int kgb = kg * 8;

    // LDS fragment bases (bf16x8-aligned, conflict-free)
    const short* xB = &Wb[(((kh * 32 + kg) * NCOL + gc) << 3)];
    const short* hB = &Wb[(((64 + kh * 64 + kg) * NCOL + gc) << 3)];
    // A-fragment base in htile: row = lane&15, k half + subgroup offset
    const short* hA = (const short*)htile + (lane & 15) * (LROW * 2) + kh * 512 + kgb;

    // coop-load geometry: thread -> (row, 16B segment)
    const int crow = tid >> 4;              // 0..15
    const int cseg = tid & 15;              // 0..15

    // x-part for one step (8 chunks/wave: k = kh*256 + cx*32 + kg*8)
    auto xpart = [&](int t, f32x4 a_cc) -> f32x4 {
        const float* xrow = p.x + ((size_t)arow * SS + t) * DD;
        #pragma unroll 4
        for (int cx = 0; cx < 8; ++cx) {
            const int k0 = kh * 256 + cx * 32 + kgb;
            f32x4 a0 = *(const f32x4*)(xrow + k0);
            f32x4 a1 = *(const f32x4*)(xrow + k0 + 4);
            bf16x8 a;
            a[0] = f2bf(a0[0]); a[1] = f2bf(a0[1]);
            a[2] = f2bf(a0[2]); a[3] = f2bf(a0[3]);
            a[4] = f2bf(a1[0]); a[5] = f2bf(a1[1]);
            a[6] = f2bf(a1[2]); a[7] = f2bf(a1[3]);
            a_cc = __builtin_amdgcn_mfma_f32_16x16x32_bf16(
                a, *(const bf16x8*)(xB + (size_t)cx * 1024), a_cc, 0, 0, 0);
        }
        return a_cc;
    };

    f32x4 acc = {0.f, 0.f, 0.f, 0.f};
    acc = xpart(0, acc);                   // prologue: x-part of t=0

    for (int t = 0; t < SS; ++t) {
        if (t > 0) {
            // ---- wait: all 128 group blocks finished step t-1 ----
            if (wave == 0) {
                const int s0 = gid * GBLK + lane * 2;
                unsigned it = 0;
                for (;;) {
                    unsigned v0 = ldflag(s0), v1 = ldflag(s0 + 1);
                    if (__all(min(v0, v1) >= (unsigned)t)) break;
                    __builtin_amdgcn_s_sleep(2);
                    if (++it > (1u << 20)) break;   // fail loud, not hang
                }
                if (lane == 0)
                    __hip_atomic_store(&rel, (unsigned)t, __ATOMIC_RELAXED,
                                       __HIP_MEMORY_SCOPE_WORKGROUP);
            } else {
                unsigned it = 0;
                while (__hip_atomic_load(&rel, __ATOMIC_RELAXED,
                                         __HIP_MEMORY_SCOPE_WORKGROUP) < (unsigned)t) {
                    __builtin_amdgcn_s_sleep(1);
                    if (++it > (1u << 22)) break;
                }
            }
            asm volatile("" ::: "memory");

            // ---- coop dedup load: group h (32 KB unique) -> LDS, once ----
            {
                const unsigned* src = g_hws + ((t - 1) & 1) * (BB * HW2)
                                    + (size_t)(bb0 + crow) * HW2 + cseg * 4;
                u32x4 v0, v1, v2, v3, v4, v5, v6, v7;
#define LDH(dst, OFF) asm volatile("global_load_dwordx4 %0, %1, off offset:" OFF " sc0 sc1" \
                                   : "=v"(dst) : "v"(src))
                LDH(v0, "0");    LDH(v1, "256");  LDH(v2, "512");  LDH(v3, "768");
                LDH(v4, "1024"); LDH(v5, "1280"); LDH(v6, "1536"); LDH(v7, "1792");
#undef LDH
                asm volatile("s_waitcnt vmcnt(0)" ::: "memory");
                __builtin_amdgcn_sched_barrier(0);
                unsigned* dst = &htile[crow * LROW + cseg * 4];
                *(u32x4*)(dst)       = v0; *(u32x4*)(dst + 64)  = v1;
                *(u32x4*)(dst + 128) = v2; *(u32x4*)(dst + 192) = v3;
                *(u32x4*)(dst + 256) = v4; *(u32x4*)(dst + 320) = v5;
                *(u32x4*)(dst + 384) = v6; *(u32x4*)(dst + 448) = v7;
            }
            __syncthreads();

            // ---- h-part: 16x (ds_read_b128 A from htile + ds B) ----
#define FMH(CH) { bf16x8 av = *(const bf16x8*)(hA + (CH) * 32);                \
        acc = __builtin_amdgcn_mfma_f32_16x16x32_bf16(                         \
            av, *(const bf16x8*)(hB + (CH) * 1024), acc, 0, 0, 0); }
            FMH(0)  FMH(1)  FMH(2)  FMH(3)
            FMH(4)  FMH(5)  FMH(6)  FMH(7)
            FMH(8)  FMH(9)  FMH(10) FMH(11)
            FMH(12) FMH(13) FMH(14) FMH(15)
#undef FMH
        }
        #pragma unroll
        for (int i = 0; i < 4; ++i)
            accl[kh][(lane >> 4) * 4 + i][gc] = acc[i];
        __syncthreads();

        if (tid < 64) {                    // gating: lane -> (batch, col-pair)
            const int b = lane >> 2, jp = (lane & 3) * 2;
            float hn2[2], cn2[2];
            #pragma unroll
            for (int u = 0; u < 2; ++u) {
                const int j = jp + u;
                float pre[4];
                #pragma unroll
                for (int g = 0; g < 4; ++g) {
                    const int c = g * 8 + j;
                    pre[g] = accl[0][b][c] + accl[1][b][c] + bias_l[c];
                }
                const float ig = 1.f / (1.f + __expf(-pre[0]));
                const float fg = 1.f / (1.f + __expf(-pre[1]));
                const float gg = tanhf(pre[2]);
                const float og = 1.f / (1.f + __expf(-pre[3]));
                const float cp = (t == 0) ? 0.f : c_st[b][j];
                const float cn = fg * cp + ig * gg;
                const float hn = og * tanhf(cn);
                c_st[b][j] = cn;
                hn2[u] = hn; cn2[u] = cn;
            }
            const unsigned pack = (unsigned)(unsigned short)f2bf(hn2[0])
                                | ((unsigned)(unsigned short)f2bf(hn2[1]) << 16);
            __hip_atomic_store(
                &g_hws[(t & 1) * (BB * HW2) + (bb0 + b) * HW2 + ((hc0 + jp) >> 1)],
                pack, __ATOMIC_RELAXED, __HIP_MEMORY_SCOPE_AGENT);
            // wave-level ack: all lanes' h-stores reached the coherence point
            asm volatile("s_waitcnt vmcnt(0)" ::: "memory");
            if (lane == 0 && t < SS - 1)
                __hip_atomic_store(&g_flag[(gid * GBLK + lid) << 4], (unsigned)(t + 1),
                                   __ATOMIC_RELAXED, __HIP_MEMORY_SCOPE_AGENT);
            // fp32 outputs off the critical path, after the flag
            const size_t o = ((size_t)(bb0 + b) * SS + t) * HH + hc0 + jp;
            *(float2*)&p.out_h[o] = make_float2(hn2[0], hn2[1]);
            *(float2*)&p.out_c[o] = make_float2(cn2[0], cn2[1]);
        }
        if (t == SS - 1) break;
        // ---- hide barrier propagation: x-part of t+1 (h-independent) ----
        acc = (f32x4){0.f, 0.f, 0.f, 0.f};
        acc = xpart(t + 1, acc);
    }

    // ---- end-of-run: last block resets flags for the next graph replay ----
    __syncthreads();
    if (tid == 0) {
        unsigned v = __hip_atomic_fetch_add(&g_done, 1u, __ATOMIC_RELAXED,
                                            __HIP_MEMORY_SCOPE_AGENT) + 1;
        if (v == NBLK) {
            for (int i = 0; i < NBLK; ++i)
                __hip_atomic_store(&g_flag[i << 4], 0u, __ATOMIC_RELAXED,
                                   __HIP_MEMORY_SCOPE_AGENT);
            __hip_atomic_store(&g_done, 0u, __ATOMIC_RELAXED,
                               __HIP_MEMORY_SCOPE_AGENT);
        }
    }
}

extern "C" void kernel_launch(void* const* d_in, const int* in_sizes, int n_in,
                              void* d_out, int out_size, void* d_ws, size_t ws_size,
                              hipStream_t stream) {
    (void)in_sizes; (void)n_in; (void)d_ws; (void)ws_size; (void)out_size;
    Params p;
    p.x = (const float*)d_in[0];
    for (int g = 0; g < 4; ++g) {
        p.Wi[g]   = (const float*)d_in[1 + g];
        p.Wh[g]   = (const float*)d_in[5 + g];
        p.bias[g] = (const float*)d_in[9 + g];
    }
    p.out_h = (float*)d_out;
    p.out_c = p.out_h + (size_t)BB * SS * HH;
    lstm_mfma<<<dim3(NBLK), dim3(256), 0, stream>>>(p);
}